// Round 13
// baseline (317.570 us; speedup 1.0000x reference)
//
#include <hip/hip_runtime.h>

// Seq2seq LSTM, round 13: r12 compute (verified PASS, 285us) rescheduled as
// TWO independent row-groups per block, anti-phased so MFMA of one group
// overlaps the transcendental cell-update of the other in every phase.
// 256 blocks x 16 rows (group0 = rows 0..7, group1 = rows 8..15), 512 thr.
// Encoder phase A: MFMA0(s) || trans1(s-1) || x1(s)-write; barrier.
//         phase B: MFMA1(s) || trans0(s)   || x0(s+1)-write; barrier.
// One barrier per group-step (was 2). Decoder adds y-proj sub-barriers.
// All compute/layout pieces byte-identical to r12; prep unchanged.
//   i,f,o gates scaled by -log2e -> sigmoid = rcp(1 + exp2(g))
//   g gate scaled by +2*log2e   -> tanh    = 1 - 2*rcp(1 + exp2(g))

#define NTHREADS 512
#define NBLOCKS  256
#define L2E 1.4426950408889634f

typedef __attribute__((ext_vector_type(8))) short short8;
typedef __attribute__((ext_vector_type(4))) float f32x4;

#define FRAG_ELEMS 51200
#define BIAS_BYTE_OFF 204800

__device__ __forceinline__ unsigned short f2bf(float f) {
    unsigned int u = __float_as_uint(f);
    return (unsigned short)((u + 0x7fff + ((u >> 16) & 1)) >> 16);   // RNE
}
__device__ __forceinline__ float bf2f(unsigned short s) {
    return __uint_as_float(((unsigned int)s) << 16);
}
__device__ __forceinline__ float ex2(float x) {
    float r; asm("v_exp_f32 %0, %1" : "=v"(r) : "v"(x)); return r;
}
__device__ __forceinline__ float rcpf_(float x) { return __builtin_amdgcn_rcpf(x); }

__device__ __forceinline__ float cellup(const f32x4 g, float& c) {
    float si = rcpf_(1.f + ex2(g[0]));
    float sf = rcpf_(1.f + ex2(g[1]));
    float tg = fmaf(-2.f, rcpf_(1.f + ex2(g[2])), 1.f);
    float so = rcpf_(1.f + ex2(g[3]));
    c = fmaf(sf, c, si * tg);
    float tc = fmaf(-2.f, rcpf_(1.f + ex2(c * (2.f * L2E))), 1.f);
    return so * tc;
}

// frag[((t*4+s)*64 + lane)*8 + e] = scale(gate) * WT'[k][n], bf16
// k = s*32+(lane>>4)*8+e, n = t*16+(lane&15), n = 4*jcol + gate  (r5/r12-identical)
__global__ void prep_kernel(const float* __restrict__ Wih_e, const float* __restrict__ Whh_e,
                            const float* __restrict__ bih_e, const float* __restrict__ bhh_e,
                            const float* __restrict__ Wih_d, const float* __restrict__ Whh_d,
                            const float* __restrict__ bih_d, const float* __restrict__ bhh_d,
                            void* __restrict__ ws)
{
    unsigned short* frag = (unsigned short*)ws;
    float* bias = (float*)((char*)ws + BIAS_BYTE_OFF);
    int gid = blockIdx.x * blockDim.x + threadIdx.x;
    int gsz = gridDim.x * blockDim.x;
    for (int i = gid; i < 2 * FRAG_ELEMS; i += gsz) {
        int which = i / FRAG_ELEMS;
        int e = i - which * FRAG_ELEMS;
        int j8 = e & 7, lane = (e >> 3) & 63, s = (e >> 9) & 3, t = e >> 11;
        int k = s * 32 + (lane >> 4) * 8 + j8;
        int n = t * 16 + (lane & 15);
        int jcol = n >> 2, gate = n & 3, col = gate * 100 + jcol;
        float scale = (gate == 2) ? (2.f * L2E) : -L2E;
        const float* Whh = which ? Whh_d : Whh_e;
        const float* Wih = which ? Wih_d : Wih_e;
        float v = 0.f;
        if (k < 100)      v = Whh[col * 100 + k];
        else if (k < 104) v = Wih[col * 4 + (k - 100)];
        frag[i] = f2bf(v * scale);
    }
    for (int i = gid; i < 800; i += gsz) {
        int which = i / 400, n = i - which * 400;
        int jcol = n >> 2, gate = n & 3, col = gate * 100 + jcol;
        float scale = (gate == 2) ? (2.f * L2E) : -L2E;
        bias[i] = scale * (which ? (bih_d[col] + bhh_d[col]) : (bih_e[col] + bhh_e[col]));
    }
}

__global__ __launch_bounds__(NTHREADS)
__attribute__((amdgpu_waves_per_eu(2)))
void seq2seq_kernel(
    const float* __restrict__ inputs,   // [200][4096][4]
    const void* __restrict__ ws,
    const float* __restrict__ Wy,       // [4][100]
    const float* __restrict__ by_g,     // [4]
    float* __restrict__ out)            // [30][4096][4]
{
    // per-group A: A[row][k] bf16 at elem ((k>>3)*16+row)*8+(k&7); rows 8..15 = 0
    __shared__ unsigned short A_frag[2][2048];   // 8 KB
    __shared__ float G_lds[2][8 * 404];          // 25.9 KB
    __shared__ unsigned short xstage[200 * 64];  // 25.6 KB: x[200][16 rows][4] bf16
    __shared__ float Wy_lds[404];

    const unsigned short* fragE = (const unsigned short*)ws;
    const unsigned short* fragD = fragE + FRAG_ELEMS;
    const float* biasE = (const float*)((const char*)ws + BIAS_BYTE_OFF);
    const float* biasD = biasE + 400;

    const int tid = threadIdx.x;
    const int wid = tid >> 6;
    const int wl  = tid & 63;
    const int m   = wl & 15;
    const int q   = wl >> 4;
    const int blk = blockIdx.x;

    for (int i = tid; i < 4096; i += NTHREADS) (&A_frag[0][0])[i] = 0;

    // xstage fill (vectorized: one float4 = one row's 4 comps)
    for (int i = tid; i < 200 * 16; i += NTHREADS) {
        int s = i >> 4, u4 = i & 15;
        float4 v = *(const float4*)&inputs[((size_t)s * 4096 + blk * 16 + u4) * 4];
        unsigned int pk01, pk23;
        asm("v_cvt_pk_bf16_f32 %0, %1, %2" : "=v"(pk01) : "v"(v.x), "v"(v.y));
        asm("v_cvt_pk_bf16_f32 %0, %1, %2" : "=v"(pk23) : "v"(v.z), "v"(v.w));
        *(unsigned int*)&xstage[s * 64 + u4 * 4]     = pk01;
        *(unsigned int*)&xstage[s * 64 + u4 * 4 + 2] = pk23;
    }

    // trans mapping: threads 0..399, cells (cr, 2jp) (cr, 2jp+1) per group
    const int cr = tid & 7, jp = tid >> 3, j0 = 2 * jp;
    const bool isc = (tid < 400);
    float cst0[2] = {0.f, 0.f}, cst1[2] = {0.f, 0.f};

    // x writers: tid 448..511 -> xu 0..63, row16 = xu>>2, group = xu>>5
    const bool isx = (tid >= 448);
    const int xu = tid - 448;
    const int xg = xu >> 5;
    const int xrl = (xu >> 2) & 7, xc = xu & 3;
    const int xelem = (192 + xrl) * 8 + 4 + xc;

    // weights (r12 pattern): 3 tiles/wave + tile 24 on wave 7
    short8 bfr[3][4]; float breg[3];
    short8 bfr24[4];  float breg24 = 0.f;
    #pragma unroll
    for (int i = 0; i < 3; ++i) {
        int t = wid + 8 * i;
        #pragma unroll
        for (int s = 0; s < 4; ++s)
            bfr[i][s] = *(const short8*)&fragE[((t * 4 + s) * 64 + wl) * 8];
        breg[i] = biasE[t * 16 + m];
    }
    if (wid == 7) {
        #pragma unroll
        for (int s = 0; s < 4; ++s)
            bfr24[s] = *(const short8*)&fragE[((24 * 4 + s) * 64 + wl) * 8];
        breg24 = biasE[24 * 16 + m];
    }

    auto do_mfma = [&](const unsigned short* Ab, float* Gb) {
        short8 af[4];
        #pragma unroll
        for (int s4 = 0; s4 < 4; ++s4)
            af[s4] = *(const short8*)&Ab[(s4 * 64 + wl) * 8];
        #pragma unroll
        for (int i = 0; i < 3; ++i) {
            int t = wid + 8 * i;
            f32x4 acc = {breg[i], breg[i], breg[i], breg[i]};
            #pragma unroll
            for (int s4 = 0; s4 < 4; ++s4)
                acc = __builtin_amdgcn_mfma_f32_16x16x32_bf16(af[s4], bfr[i][s4], acc, 0, 0, 0);
            if (q < 2) {
                #pragma unroll
                for (int r = 0; r < 4; ++r)
                    Gb[(q * 4 + r) * 404 + t * 16 + m] = acc[r];
            }
        }
        if (wid == 7) {
            f32x4 acc = {breg24, breg24, breg24, breg24};
            #pragma unroll
            for (int s4 = 0; s4 < 4; ++s4)
                acc = __builtin_amdgcn_mfma_f32_16x16x32_bf16(af[s4], bfr24[s4], acc, 0, 0, 0);
            if (q < 2) {
                #pragma unroll
                for (int r = 0; r < 4; ++r)
                    Gb[(q * 4 + r) * 404 + 24 * 16 + m] = acc[r];
            }
        }
    };

    auto do_trans = [&](const float* Gb, unsigned short* Ab, float* cs) {
        if (isc) {
            f32x4 ga = *(const f32x4*)&Gb[cr * 404 + 8 * jp];
            f32x4 gb = *(const f32x4*)&Gb[cr * 404 + 8 * jp + 4];
            float h0 = cellup(ga, cs[0]);
            float h1 = cellup(gb, cs[1]);
            unsigned int pk;
            asm("v_cvt_pk_bf16_f32 %0, %1, %2" : "=v"(pk) : "v"(h0), "v"(h1));
            *(unsigned int*)&Ab[((j0 >> 3) * 16 + cr) * 8 + (j0 & 7)] = pk;
        }
    };

    auto do_yproj = [&](unsigned short* Ab, int g, int d) {
        if (tid < 256) {
            int yrow = tid >> 5, yln = tid & 31;
            float p0 = 0.f, p1 = 0.f, p2 = 0.f, p3 = 0.f;
            #pragma unroll
            for (int i = 0; i < 4; ++i) {
                int j = yln + 32 * i;
                if (j < 100) {
                    float hv = bf2f(Ab[((j >> 3) * 16 + yrow) * 8 + (j & 7)]);
                    p0 = fmaf(Wy_lds[0 * 100 + j], hv, p0);
                    p1 = fmaf(Wy_lds[1 * 100 + j], hv, p1);
                    p2 = fmaf(Wy_lds[2 * 100 + j], hv, p2);
                    p3 = fmaf(Wy_lds[3 * 100 + j], hv, p3);
                }
            }
            #pragma unroll
            for (int mm = 16; mm >= 1; mm >>= 1) {
                p0 += __shfl_xor(p0, mm, 32);
                p1 += __shfl_xor(p1, mm, 32);
                p2 += __shfl_xor(p2, mm, 32);
                p3 += __shfl_xor(p3, mm, 32);
            }
            if (yln == 0) {
                float y0 = p0 + Wy_lds[400], y1 = p1 + Wy_lds[401];
                float y2 = p2 + Wy_lds[402], y3 = p3 + Wy_lds[403];
                *(float4*)&out[((size_t)d * 4096 + blk * 16 + g * 8 + yrow) * 4] =
                    make_float4(y0, y1, y2, y3);
                unsigned int pk01, pk23;
                asm("v_cvt_pk_bf16_f32 %0, %1, %2" : "=v"(pk01) : "v"(y0), "v"(y1));
                asm("v_cvt_pk_bf16_f32 %0, %1, %2" : "=v"(pk23) : "v"(y2), "v"(y3));
                *(unsigned int*)&Ab[(192 + yrow) * 8 + 4] = pk01;   // y feedback
                *(unsigned int*)&Ab[(192 + yrow) * 8 + 6] = pk23;
            }
        }
    };

    __syncthreads();                             // A zeroed + xstage filled
    if (isx && xg == 0) A_frag[0][xelem] = xstage[xu];   // x0(0)
    __syncthreads();

    // ---------------- encoder: 200 steps, 2 anti-phased groups ----------------
    for (int s = 0; s < 200; ++s) {
        // PHASE A: MFMA0(s) || trans1(s-1) || x1(s)
        do_mfma(A_frag[0], G_lds[0]);
        if (s) do_trans(G_lds[1], A_frag[1], cst1);
        if (isx && xg == 1) A_frag[1][xelem] = xstage[s * 64 + xu];
        __syncthreads();
        // PHASE B: MFMA1(s) || trans0(s) || x0(s+1)
        do_mfma(A_frag[1], G_lds[1]);
        do_trans(G_lds[0], A_frag[0], cst0);
        if (isx && xg == 0 && s < 199) A_frag[0][xelem] = xstage[(s + 1) * 64 + xu];
        __syncthreads();
    }
    do_trans(G_lds[1], A_frag[1], cst1);         // drain: h1_enc(199)

    // ---------------- switch to decoder ----------------
    #pragma unroll
    for (int i = 0; i < 3; ++i) {
        int t = wid + 8 * i;
        #pragma unroll
        for (int s = 0; s < 4; ++s)
            bfr[i][s] = *(const short8*)&fragD[((t * 4 + s) * 64 + wl) * 8];
        breg[i] = biasD[t * 16 + m];
    }
    if (wid == 7) {
        #pragma unroll
        for (int s = 0; s < 4; ++s)
            bfr24[s] = *(const short8*)&fragD[((24 * 4 + s) * 64 + wl) * 8];
        breg24 = biasD[24 * 16 + m];
    }
    cst0[0] = cst0[1] = cst1[0] = cst1[1] = 0.f; // c resets; h carries over
    if (isx) A_frag[xg][xelem] = 0;              // y_prev = 0, both groups
    for (int i = tid; i < 404; i += NTHREADS)
        Wy_lds[i] = (i < 400) ? Wy[i] : by_g[i - 400];
    __syncthreads();

    // ---------------- decoder: 30 steps, anti-phased + y sub-barriers ----------------
    for (int d = 0; d < 30; ++d) {
        // PHASE A: MFMA0(d) || trans1(d-1); then y1(d-1)
        do_mfma(A_frag[0], G_lds[0]);
        if (d) do_trans(G_lds[1], A_frag[1], cst1);
        __syncthreads();
        if (d) do_yproj(A_frag[1], 1, d - 1);
        __syncthreads();
        // PHASE B: MFMA1(d) || trans0(d); then y0(d)
        do_mfma(A_frag[1], G_lds[1]);
        do_trans(G_lds[0], A_frag[0], cst0);
        __syncthreads();
        do_yproj(A_frag[0], 0, d);
        __syncthreads();
    }
    do_trans(G_lds[1], A_frag[1], cst1);         // drain: h1_dec(29)
    __syncthreads();
    do_yproj(A_frag[1], 1, 29);                  // y1(29)
}

extern "C" void kernel_launch(void* const* d_in, const int* in_sizes, int n_in,
                              void* d_out, int out_size, void* d_ws, size_t ws_size,
                              hipStream_t stream)
{
    (void)in_sizes; (void)n_in; (void)out_size; (void)ws_size;
    const float* inputs = (const float*)d_in[0];
    const float* Wih_e  = (const float*)d_in[1];
    const float* Whh_e  = (const float*)d_in[2];
    const float* bih_e  = (const float*)d_in[3];
    const float* bhh_e  = (const float*)d_in[4];
    const float* Wih_d  = (const float*)d_in[5];
    const float* Whh_d  = (const float*)d_in[6];
    const float* bih_d  = (const float*)d_in[7];
    const float* bhh_d  = (const float*)d_in[8];
    const float* Wy     = (const float*)d_in[9];
    const float* by     = (const float*)d_in[10];
    float* out = (float*)d_out;

    hipLaunchKernelGGL(prep_kernel, dim3(256), dim3(256), 0, stream,
                       Wih_e, Whh_e, bih_e, bhh_e, Wih_d, Whh_d, bih_d, bhh_d, d_ws);
    hipLaunchKernelGGL(seq2seq_kernel, dim3(NBLOCKS), dim3(NTHREADS), 0, stream,
                       inputs, d_ws, Wy, by, out);
}

// Round 14
// 243.073 us; speedup vs baseline: 1.3065x; 1.3065x over previous
//
#include <hip/hip_runtime.h>

// Seq2seq LSTM, round 14: r12 skeleton (verified PASS, 285us) at FULL MFMA M.
// 256 blocks x 1024 threads x BR=16 rows: same 16 waves/CU as r12, but every
// MFMA computes 16 real batch rows (r12 wasted rows 8..15) -> per-CU MFMA work
// halves. All pieces (fragment layouts, prep, B1/B2 barriers, G round-trip,
// LDS x-staging, pair-packed h writes) are verbatim from verified kernels.
//   i,f,o gates scaled by -log2e -> sigmoid = rcp(1 + exp2(g))
//   g gate scaled by +2*log2e   -> tanh    = 1 - 2*rcp(1 + exp2(g))

#define NTHREADS 1024
#define NBLOCKS  256
#define BR       16

typedef __attribute__((ext_vector_type(8))) short short8;
typedef __attribute__((ext_vector_type(4))) float f32x4;

#define FRAG_ELEMS 51200
#define BIAS_BYTE_OFF 204800
#define L2E 1.4426950408889634f

__device__ __forceinline__ unsigned short f2bf(float f) {
    unsigned int u = __float_as_uint(f);
    return (unsigned short)((u + 0x7fff + ((u >> 16) & 1)) >> 16);   // RNE
}
__device__ __forceinline__ float bf2f(unsigned short s) {
    return __uint_as_float(((unsigned int)s) << 16);
}
__device__ __forceinline__ float ex2(float x) {
    float r; asm("v_exp_f32 %0, %1" : "=v"(r) : "v"(x)); return r;
}
__device__ __forceinline__ float rcpf_(float x) { return __builtin_amdgcn_rcpf(x); }

__device__ __forceinline__ float cellup(const f32x4 g, float& c) {
    float si = rcpf_(1.f + ex2(g[0]));
    float sf = rcpf_(1.f + ex2(g[1]));
    float tg = fmaf(-2.f, rcpf_(1.f + ex2(g[2])), 1.f);
    float so = rcpf_(1.f + ex2(g[3]));
    c = fmaf(sf, c, si * tg);
    float tc = fmaf(-2.f, rcpf_(1.f + ex2(c * (2.f * L2E))), 1.f);
    return so * tc;
}

// frag[((t*4+s)*64 + lane)*8 + e] = scale(gate) * WT'[k][n], bf16
// k = s*32+(lane>>4)*8+e, n = t*16+(lane&15), n = 4*jcol + gate  (r5/r12-identical)
__global__ void prep_kernel(const float* __restrict__ Wih_e, const float* __restrict__ Whh_e,
                            const float* __restrict__ bih_e, const float* __restrict__ bhh_e,
                            const float* __restrict__ Wih_d, const float* __restrict__ Whh_d,
                            const float* __restrict__ bih_d, const float* __restrict__ bhh_d,
                            void* __restrict__ ws)
{
    unsigned short* frag = (unsigned short*)ws;
    float* bias = (float*)((char*)ws + BIAS_BYTE_OFF);
    int gid = blockIdx.x * blockDim.x + threadIdx.x;
    int gsz = gridDim.x * blockDim.x;
    for (int i = gid; i < 2 * FRAG_ELEMS; i += gsz) {
        int which = i / FRAG_ELEMS;
        int e = i - which * FRAG_ELEMS;
        int j8 = e & 7, lane = (e >> 3) & 63, s = (e >> 9) & 3, t = e >> 11;
        int k = s * 32 + (lane >> 4) * 8 + j8;
        int n = t * 16 + (lane & 15);
        int jcol = n >> 2, gate = n & 3, col = gate * 100 + jcol;
        float scale = (gate == 2) ? (2.f * L2E) : -L2E;
        const float* Whh = which ? Whh_d : Whh_e;
        const float* Wih = which ? Wih_d : Wih_e;
        float v = 0.f;
        if (k < 100)      v = Whh[col * 100 + k];
        else if (k < 104) v = Wih[col * 4 + (k - 100)];
        frag[i] = f2bf(v * scale);
    }
    for (int i = gid; i < 800; i += gsz) {
        int which = i / 400, n = i - which * 400;
        int jcol = n >> 2, gate = n & 3, col = gate * 100 + jcol;
        float scale = (gate == 2) ? (2.f * L2E) : -L2E;
        bias[i] = scale * (which ? (bih_d[col] + bhh_d[col]) : (bih_e[col] + bhh_e[col]));
    }
}

__global__ __launch_bounds__(NTHREADS, 4)
void seq2seq_kernel(
    const float* __restrict__ inputs,   // [200][4096][4]
    const void* __restrict__ ws,
    const float* __restrict__ Wy,       // [4][100]
    const float* __restrict__ by_g,     // [4]
    float* __restrict__ out)            // [30][4096][4]
{
    // A: A[row][k] bf16 at elem ((k>>3)*16+row)*8+(k&7), rows 0..15 all real
    __shared__ unsigned short A_frag[2048];      // 4 KB
    __shared__ float G_lds[BR * 404];            // 25.9 KB
    __shared__ float Wy_lds[404];
    __shared__ unsigned short xstage[200 * 64];  // 25.6 KB: x[200][16][4] bf16

    const unsigned short* fragE = (const unsigned short*)ws;
    const unsigned short* fragD = fragE + FRAG_ELEMS;
    const float* biasE = (const float*)((const char*)ws + BIAS_BYTE_OFF);
    const float* biasD = biasE + 400;

    const int tid = threadIdx.x;
    const int wid = tid >> 6;          // wave 0..15
    const int wl  = tid & 63;
    const int m   = wl & 15;           // A row / C col
    const int q   = wl >> 4;
    const int blk = blockIdx.x;

    for (int i = tid; i < 2048; i += NTHREADS) A_frag[i] = 0;

    // bulk x staging (vectorized): xstage[s*64 + row*4 + c]
    for (int i = tid; i < 200 * 16; i += NTHREADS) {
        int s = i >> 4, u4 = i & 15;
        float4 v = *(const float4*)&inputs[((size_t)s * 4096 + blk * BR + u4) * 4];
        unsigned int pk01, pk23;
        asm("v_cvt_pk_bf16_f32 %0, %1, %2" : "=v"(pk01) : "v"(v.x), "v"(v.y));
        asm("v_cvt_pk_bf16_f32 %0, %1, %2" : "=v"(pk23) : "v"(v.z), "v"(v.w));
        *(unsigned int*)&xstage[i * 4]     = pk01;
        *(unsigned int*)&xstage[i * 4 + 2] = pk23;
    }

    // trans mapping: tid<800 owns cells (cr, 2jp) and (cr, 2jp+1)
    const int cr = tid & 15, jp = tid >> 4, j0 = 2 * jp;
    const bool isc = (tid < 800);
    float cst[2] = {0.f, 0.f};

    // x writers: tid 960..1023 -> (row 0..15, comp 0..3)
    const bool isx = (tid >= 960);
    const int xu = tid - 960;
    const int xr = xu >> 2, xc = xu & 3;
    const int xelem = (192 + xr) * 8 + 4 + xc;   // k = 100+xc, row xr

    // weights: up to 2 tiles per wave (t = wid, wid+16; valid t<25)
    short8 bfr[2][4]; float breg[2] = {0.f, 0.f};
    #pragma unroll
    for (int i = 0; i < 2; ++i) {
        int t = wid + 16 * i;
        if (t < 25) {
            #pragma unroll
            for (int s = 0; s < 4; ++s)
                bfr[i][s] = *(const short8*)&fragE[((t * 4 + s) * 64 + wl) * 8];
            breg[i] = biasE[t * 16 + m];
        }
    }

    __syncthreads();                             // A zeroed + xstage filled
    if (isx) A_frag[xelem] = xstage[xu];         // x(0)

    // ---------------- encoder: 200 steps ----------------
    for (int step = 0; step < 200; ++step) {
        __syncthreads();                         // B1: A (h,x) ready
        short8 af[4];
        #pragma unroll
        for (int s = 0; s < 4; ++s)
            af[s] = *(const short8*)&A_frag[(s * 64 + wl) * 8];
        #pragma unroll
        for (int i = 0; i < 2; ++i) {
            int t = wid + 16 * i;
            if (t < 25) {
                f32x4 acc = {breg[i], breg[i], breg[i], breg[i]};
                #pragma unroll
                for (int s = 0; s < 4; ++s)
                    acc = __builtin_amdgcn_mfma_f32_16x16x32_bf16(af[s], bfr[i][s], acc, 0, 0, 0);
                #pragma unroll
                for (int r = 0; r < 4; ++r)
                    G_lds[(q * 4 + r) * 404 + t * 16 + m] = acc[r];
            }
        }
        __syncthreads();                         // B2: G ready, af reads done
        if (isc) {
            f32x4 ga = *(const f32x4*)&G_lds[cr * 404 + 8 * jp];
            f32x4 gb = *(const f32x4*)&G_lds[cr * 404 + 8 * jp + 4];
            float h0 = cellup(ga, cst[0]);
            float h1 = cellup(gb, cst[1]);
            unsigned int pk;
            asm("v_cvt_pk_bf16_f32 %0, %1, %2" : "=v"(pk) : "v"(h0), "v"(h1));
            *(unsigned int*)&A_frag[((j0 >> 3) * 16 + cr) * 8 + (j0 & 7)] = pk;
        }
        if (isx && step < 199)
            A_frag[xelem] = xstage[(step + 1) * 64 + xu];   // x(s+1), LDS->LDS
    }

    // ---------------- switch to decoder ----------------
    #pragma unroll
    for (int i = 0; i < 2; ++i) {
        int t = wid + 16 * i;
        if (t < 25) {
            #pragma unroll
            for (int s = 0; s < 4; ++s)
                bfr[i][s] = *(const short8*)&fragD[((t * 4 + s) * 64 + wl) * 8];
            breg[i] = biasD[t * 16 + m];
        }
    }
    cst[0] = cst[1] = 0.f;                       // c resets; h carries over
    if (isx) A_frag[xelem] = 0;                  // y_prev = 0
    for (int i = tid; i < 404; i += NTHREADS)
        Wy_lds[i] = (i < 400) ? Wy[i] : by_g[i - 400];

    const int yrow = tid >> 5, yln = tid & 31;
    const bool isy = (tid < 512);                // 16 rows x 32 lanes

    // ---------------- decoder: 30 autoregressive steps ----------------
    for (int step = 0; step < 30; ++step) {
        __syncthreads();                         // B1: A ready (+ Wy staged)
        short8 af[4];
        #pragma unroll
        for (int s = 0; s < 4; ++s)
            af[s] = *(const short8*)&A_frag[(s * 64 + wl) * 8];
        #pragma unroll
        for (int i = 0; i < 2; ++i) {
            int t = wid + 16 * i;
            if (t < 25) {
                f32x4 acc = {breg[i], breg[i], breg[i], breg[i]};
                #pragma unroll
                for (int s = 0; s < 4; ++s)
                    acc = __builtin_amdgcn_mfma_f32_16x16x32_bf16(af[s], bfr[i][s], acc, 0, 0, 0);
                #pragma unroll
                for (int r = 0; r < 4; ++r)
                    G_lds[(q * 4 + r) * 404 + t * 16 + m] = acc[r];
            }
        }
        __syncthreads();                         // B2: G ready
        if (isc) {
            f32x4 ga = *(const f32x4*)&G_lds[cr * 404 + 8 * jp];
            f32x4 gb = *(const f32x4*)&G_lds[cr * 404 + 8 * jp + 4];
            float h0 = cellup(ga, cst[0]);
            float h1 = cellup(gb, cst[1]);
            unsigned int pk;
            asm("v_cvt_pk_bf16_f32 %0, %1, %2" : "=v"(pk) : "v"(h0), "v"(h1));
            *(unsigned int*)&A_frag[((j0 >> 3) * 16 + cr) * 8 + (j0 & 7)] = pk;
        }
        __syncthreads();                         // B3: h complete
        if (isy) {
            float p0 = 0.f, p1 = 0.f, p2 = 0.f, p3 = 0.f;
            #pragma unroll
            for (int i = 0; i < 4; ++i) {
                int j = yln + 32 * i;
                if (j < 100) {
                    float hv = bf2f(A_frag[((j >> 3) * 16 + yrow) * 8 + (j & 7)]);
                    p0 = fmaf(Wy_lds[0 * 100 + j], hv, p0);
                    p1 = fmaf(Wy_lds[1 * 100 + j], hv, p1);
                    p2 = fmaf(Wy_lds[2 * 100 + j], hv, p2);
                    p3 = fmaf(Wy_lds[3 * 100 + j], hv, p3);
                }
            }
            #pragma unroll
            for (int mm = 16; mm >= 1; mm >>= 1) {
                p0 += __shfl_xor(p0, mm, 32);
                p1 += __shfl_xor(p1, mm, 32);
                p2 += __shfl_xor(p2, mm, 32);
                p3 += __shfl_xor(p3, mm, 32);
            }
            if (yln == 0) {
                float y0 = p0 + Wy_lds[400], y1 = p1 + Wy_lds[401];
                float y2 = p2 + Wy_lds[402], y3 = p3 + Wy_lds[403];
                float4 yv = make_float4(y0, y1, y2, y3);
                *(float4*)&out[((size_t)step * 4096 + blk * BR + yrow) * 4] = yv;
                unsigned int pk01, pk23;
                asm("v_cvt_pk_bf16_f32 %0, %1, %2" : "=v"(pk01) : "v"(y0), "v"(y1));
                asm("v_cvt_pk_bf16_f32 %0, %1, %2" : "=v"(pk23) : "v"(y2), "v"(y3));
                *(unsigned int*)&A_frag[(192 + yrow) * 8 + 4] = pk01;
                *(unsigned int*)&A_frag[(192 + yrow) * 8 + 6] = pk23;
            }
        }
    }
}

extern "C" void kernel_launch(void* const* d_in, const int* in_sizes, int n_in,
                              void* d_out, int out_size, void* d_ws, size_t ws_size,
                              hipStream_t stream)
{
    (void)in_sizes; (void)n_in; (void)out_size; (void)ws_size;
    const float* inputs = (const float*)d_in[0];
    const float* Wih_e  = (const float*)d_in[1];
    const float* Whh_e  = (const float*)d_in[2];
    const float* bih_e  = (const float*)d_in[3];
    const float* bhh_e  = (const float*)d_in[4];
    const float* Wih_d  = (const float*)d_in[5];
    const float* Whh_d  = (const float*)d_in[6];
    const float* bih_d  = (const float*)d_in[7];
    const float* bhh_d  = (const float*)d_in[8];
    const float* Wy     = (const float*)d_in[9];
    const float* by     = (const float*)d_in[10];
    float* out = (float*)d_out;

    hipLaunchKernelGGL(prep_kernel, dim3(256), dim3(256), 0, stream,
                       Wih_e, Whh_e, bih_e, bhh_e, Wih_d, Whh_d, bih_d, bhh_d, d_ws);
    hipLaunchKernelGGL(seq2seq_kernel, dim3(NBLOCKS), dim3(NTHREADS), 0, stream,
                       inputs, d_ws, Wy, by, out);
}

// Round 15
// 232.077 us; speedup vs baseline: 1.3684x; 1.0474x over previous
//
#include <hip/hip_runtime.h>

// Seq2seq LSTM, round 15: r14 base (verified PASS, 258us) with the G_lds
// round-trip replaced by r10's VERIFIED quad-transpose (PASS at r10), now
// implemented with mov_dpp quad_perm (full-rate VALU, no LDS) instead of
// __shfl_xor (which lowers to LDS-pipe ds_bpermute). 256 blocks x 1024 thr
// x BR=16. After MFMA, lane (q, wl&3, ca) owns cell (row=q*4+(wl&3),
// col=4t+ca) -> cellup in registers, h held across B2, per-lane b16 store.
//   i,f,o gates scaled by -log2e -> sigmoid = rcp(1 + exp2(g))
//   g gate scaled by +2*log2e   -> tanh    = 1 - 2*rcp(1 + exp2(g))

#define NTHREADS 1024
#define NBLOCKS  256
#define BR       16

typedef __attribute__((ext_vector_type(8))) short short8;
typedef __attribute__((ext_vector_type(4))) float f32x4;

#define FRAG_ELEMS 51200
#define BIAS_BYTE_OFF 204800
#define L2E 1.4426950408889634f

__device__ __forceinline__ unsigned short f2bf(float f) {
    unsigned int u = __float_as_uint(f);
    return (unsigned short)((u + 0x7fff + ((u >> 16) & 1)) >> 16);   // RNE
}
__device__ __forceinline__ float bf2f(unsigned short s) {
    return __uint_as_float(((unsigned int)s) << 16);
}
__device__ __forceinline__ float ex2(float x) {
    float r; asm("v_exp_f32 %0, %1" : "=v"(r) : "v"(x)); return r;
}
__device__ __forceinline__ float rcpf_(float x) { return __builtin_amdgcn_rcpf(x); }

// quad_perm DPP: lane xor 1 / xor 2 within each quad (full-rate VALU)
__device__ __forceinline__ float dppx1(float x) {
    return __int_as_float(__builtin_amdgcn_mov_dpp(__float_as_int(x), 0xB1, 0xF, 0xF, true));
}
__device__ __forceinline__ float dppx2(float x) {
    return __int_as_float(__builtin_amdgcn_mov_dpp(__float_as_int(x), 0x4E, 0xF, 0xF, true));
}

// r10-verified 4x4 quad transpose (select structure identical), DPP edition;
// then LSTM cell update on (i,f,g,o). Returns h, updates c.
__device__ __forceinline__ float trans_cell(f32x4 v, float& c, int wl) {
    float s0 = dppx1(v[0]), s1 = dppx1(v[1]), s2 = dppx1(v[2]), s3 = dppx1(v[3]);
    const bool o1 = (wl & 1) != 0;
    float a0 = o1 ? s1 : v[0];
    float a1 = o1 ? v[1] : s0;
    float a2 = o1 ? s3 : v[2];
    float a3 = o1 ? v[3] : s2;
    float u0 = dppx2(a0), u1 = dppx2(a1), u2 = dppx2(a2), u3 = dppx2(a3);
    const bool o2 = (wl & 2) != 0;
    float gi = o2 ? u2 : a0;
    float gf = o2 ? u3 : a1;
    float gg = o2 ? a2 : u0;
    float go = o2 ? a3 : u1;
    float si = rcpf_(1.f + ex2(gi));
    float sf = rcpf_(1.f + ex2(gf));
    float tg = fmaf(-2.f, rcpf_(1.f + ex2(gg)), 1.f);
    float so = rcpf_(1.f + ex2(go));
    c = fmaf(sf, c, si * tg);
    float tc = fmaf(-2.f, rcpf_(1.f + ex2(c * (2.f * L2E))), 1.f);
    return so * tc;
}

// frag[((t*4+s)*64 + lane)*8 + e] = scale(gate) * WT'[k][n], bf16
// k = s*32+(lane>>4)*8+e, n = t*16+(lane&15), n = 4*jcol + gate  (r5-identical)
__global__ void prep_kernel(const float* __restrict__ Wih_e, const float* __restrict__ Whh_e,
                            const float* __restrict__ bih_e, const float* __restrict__ bhh_e,
                            const float* __restrict__ Wih_d, const float* __restrict__ Whh_d,
                            const float* __restrict__ bih_d, const float* __restrict__ bhh_d,
                            void* __restrict__ ws)
{
    unsigned short* frag = (unsigned short*)ws;
    float* bias = (float*)((char*)ws + BIAS_BYTE_OFF);
    int gid = blockIdx.x * blockDim.x + threadIdx.x;
    int gsz = gridDim.x * blockDim.x;
    for (int i = gid; i < 2 * FRAG_ELEMS; i += gsz) {
        int which = i / FRAG_ELEMS;
        int e = i - which * FRAG_ELEMS;
        int j8 = e & 7, lane = (e >> 3) & 63, s = (e >> 9) & 3, t = e >> 11;
        int k = s * 32 + (lane >> 4) * 8 + j8;
        int n = t * 16 + (lane & 15);
        int jcol = n >> 2, gate = n & 3, col = gate * 100 + jcol;
        float scale = (gate == 2) ? (2.f * L2E) : -L2E;
        const float* Whh = which ? Whh_d : Whh_e;
        const float* Wih = which ? Wih_d : Wih_e;
        float v = 0.f;
        if (k < 100)      v = Whh[col * 100 + k];
        else if (k < 104) v = Wih[col * 4 + (k - 100)];
        frag[i] = f2bf(v * scale);
    }
    for (int i = gid; i < 800; i += gsz) {
        int which = i / 400, n = i - which * 400;
        int jcol = n >> 2, gate = n & 3, col = gate * 100 + jcol;
        float scale = (gate == 2) ? (2.f * L2E) : -L2E;
        bias[i] = scale * (which ? (bih_d[col] + bhh_d[col]) : (bih_e[col] + bhh_e[col]));
    }
}

__global__ __launch_bounds__(NTHREADS, 4)
void seq2seq_kernel(
    const float* __restrict__ inputs,   // [200][4096][4]
    const void* __restrict__ ws,
    const float* __restrict__ Wy,       // [4][100]
    const float* __restrict__ by_g,     // [4]
    float* __restrict__ out)            // [30][4096][4]
{
    // A: A[row][k] bf16 at elem ((k>>3)*16+row)*8+(k&7), rows 0..15 all real
    __shared__ unsigned short A_frag[2048];      // 4 KB
    __shared__ float Wy_lds[404];
    __shared__ unsigned short xstage[200 * 64];  // 25.6 KB: x[200][16][4] bf16

    const unsigned short* fragE = (const unsigned short*)ws;
    const unsigned short* fragD = fragE + FRAG_ELEMS;
    const float* biasE = (const float*)((const char*)ws + BIAS_BYTE_OFF);
    const float* biasD = biasE + 400;

    const int tid = threadIdx.x;
    const int wid = tid >> 6;          // wave 0..15
    const int wl  = tid & 63;
    const int m   = wl & 15;           // A row / C col
    const int q   = wl >> 4;
    const int blk = blockIdx.x;

    // cell owned after quad transpose (per tile t): row crow, col = 4t+ca
    const int crow = q * 4 + (wl & 3);
    const int ca   = (wl >> 2) & 3;

    for (int i = tid; i < 2048; i += NTHREADS) A_frag[i] = 0;

    // bulk x staging (vectorized): xstage[s*64 + row*4 + c]
    for (int i = tid; i < 200 * 16; i += NTHREADS) {
        int s = i >> 4, u4 = i & 15;
        float4 v = *(const float4*)&inputs[((size_t)s * 4096 + blk * BR + u4) * 4];
        unsigned int pk01, pk23;
        asm("v_cvt_pk_bf16_f32 %0, %1, %2" : "=v"(pk01) : "v"(v.x), "v"(v.y));
        asm("v_cvt_pk_bf16_f32 %0, %1, %2" : "=v"(pk23) : "v"(v.z), "v"(v.w));
        *(unsigned int*)&xstage[i * 4]     = pk01;
        *(unsigned int*)&xstage[i * 4 + 2] = pk23;
    }

    // x writers: tid 960..1023 -> (row 0..15, comp 0..3)
    const bool isx = (tid >= 960);
    const int xu = tid - 960;
    const int xr = xu >> 2, xc = xu & 3;
    const int xelem = (192 + xr) * 8 + 4 + xc;   // k = 100+xc, row xr

    // weights: up to 2 tiles per wave (t = wid, wid+16; valid t<25)
    short8 bfr[2][4]; float breg[2] = {0.f, 0.f};
    #pragma unroll
    for (int i = 0; i < 2; ++i) {
        int t = wid + 16 * i;
        if (t < 25) {
            #pragma unroll
            for (int s = 0; s < 4; ++s)
                bfr[i][s] = *(const short8*)&fragE[((t * 4 + s) * 64 + wl) * 8];
            breg[i] = biasE[t * 16 + m];
        }
    }
    float cst[2] = {0.f, 0.f};

    __syncthreads();                             // A zeroed + xstage filled
    if (isx) A_frag[xelem] = xstage[xu];         // x(0)

    // ---------------- encoder: 200 steps ----------------
    for (int step = 0; step < 200; ++step) {
        __syncthreads();                         // B1: A (h,x) ready
        short8 af[4];
        #pragma unroll
        for (int s = 0; s < 4; ++s)
            af[s] = *(const short8*)&A_frag[(s * 64 + wl) * 8];
        float hreg[2];
        #pragma unroll
        for (int i = 0; i < 2; ++i) {
            int t = wid + 16 * i;
            if (t < 25) {
                f32x4 acc = {breg[i], breg[i], breg[i], breg[i]};
                #pragma unroll
                for (int s = 0; s < 4; ++s)
                    acc = __builtin_amdgcn_mfma_f32_16x16x32_bf16(af[s], bfr[i][s], acc, 0, 0, 0);
                hreg[i] = trans_cell(acc, cst[i], wl);
            }
        }
        __syncthreads();                         // B2: all af reads done
        #pragma unroll
        for (int i = 0; i < 2; ++i) {
            int t = wid + 16 * i;
            if (t < 25) {
                int col = 4 * t + ca;
                A_frag[((col >> 3) * 16 + crow) * 8 + (col & 7)] = f2bf(hreg[i]);
            }
        }
        if (isx && step < 199)
            A_frag[xelem] = xstage[(step + 1) * 64 + xu];   // x(s+1), LDS->LDS
    }

    // ---------------- switch to decoder ----------------
    #pragma unroll
    for (int i = 0; i < 2; ++i) {
        int t = wid + 16 * i;
        if (t < 25) {
            #pragma unroll
            for (int s = 0; s < 4; ++s)
                bfr[i][s] = *(const short8*)&fragD[((t * 4 + s) * 64 + wl) * 8];
            breg[i] = biasD[t * 16 + m];
        }
    }
    cst[0] = cst[1] = 0.f;                       // c resets; h carries over
    if (isx) A_frag[xelem] = 0;                  // y_prev = 0
    for (int i = tid; i < 404; i += NTHREADS)
        Wy_lds[i] = (i < 400) ? Wy[i] : by_g[i - 400];

    const int yrow = tid >> 5, yln = tid & 31;
    const bool isy = (tid < 512);                // 16 rows x 32 lanes

    // ---------------- decoder: 30 autoregressive steps ----------------
    for (int step = 0; step < 30; ++step) {
        __syncthreads();                         // B1: A ready (+ Wy staged)
        short8 af[4];
        #pragma unroll
        for (int s = 0; s < 4; ++s)
            af[s] = *(const short8*)&A_frag[(s * 64 + wl) * 8];
        float hreg[2];
        #pragma unroll
        for (int i = 0; i < 2; ++i) {
            int t = wid + 16 * i;
            if (t < 25) {
                f32x4 acc = {breg[i], breg[i], breg[i], breg[i]};
                #pragma unroll
                for (int s = 0; s < 4; ++s)
                    acc = __builtin_amdgcn_mfma_f32_16x16x32_bf16(af[s], bfr[i][s], acc, 0, 0, 0);
                hreg[i] = trans_cell(acc, cst[i], wl);
            }
        }
        __syncthreads();                         // B2: af reads done
        #pragma unroll
        for (int i = 0; i < 2; ++i) {
            int t = wid + 16 * i;
            if (t < 25) {
                int col = 4 * t + ca;
                A_frag[((col >> 3) * 16 + crow) * 8 + (col & 7)] = f2bf(hreg[i]);
            }
        }
        __syncthreads();                         // B3: h complete
        if (isy) {
            float p0 = 0.f, p1 = 0.f, p2 = 0.f, p3 = 0.f;
            #pragma unroll
            for (int i = 0; i < 4; ++i) {
                int j = yln + 32 * i;
                if (j < 100) {
                    float hv = bf2f(A_frag[((j >> 3) * 16 + yrow) * 8 + (j & 7)]);
                    p0 = fmaf(Wy_lds[0 * 100 + j], hv, p0);
                    p1 = fmaf(Wy_lds[1 * 100 + j], hv, p1);
                    p2 = fmaf(Wy_lds[2 * 100 + j], hv, p2);
                    p3 = fmaf(Wy_lds[3 * 100 + j], hv, p3);
                }
            }
            #pragma unroll
            for (int mm = 16; mm >= 1; mm >>= 1) {
                p0 += __shfl_xor(p0, mm, 32);
                p1 += __shfl_xor(p1, mm, 32);
                p2 += __shfl_xor(p2, mm, 32);
                p3 += __shfl_xor(p3, mm, 32);
            }
            if (yln == 0) {
                float y0 = p0 + Wy_lds[400], y1 = p1 + Wy_lds[401];
                float y2 = p2 + Wy_lds[402], y3 = p3 + Wy_lds[403];
                float4 yv = make_float4(y0, y1, y2, y3);
                *(float4*)&out[((size_t)step * 4096 + blk * BR + yrow) * 4] = yv;
                unsigned int pk01, pk23;
                asm("v_cvt_pk_bf16_f32 %0, %1, %2" : "=v"(pk01) : "v"(y0), "v"(y1));
                asm("v_cvt_pk_bf16_f32 %0, %1, %2" : "=v"(pk23) : "v"(y2), "v"(y3));
                *(unsigned int*)&A_frag[(192 + yrow) * 8 + 4] = pk01;
                *(unsigned int*)&A_frag[(192 + yrow) * 8 + 6] = pk23;
            }
        }
    }
}

extern "C" void kernel_launch(void* const* d_in, const int* in_sizes, int n_in,
                              void* d_out, int out_size, void* d_ws, size_t ws_size,
                              hipStream_t stream)
{
    (void)in_sizes; (void)n_in; (void)out_size; (void)ws_size;
    const float* inputs = (const float*)d_in[0];
    const float* Wih_e  = (const float*)d_in[1];
    const float* Whh_e  = (const float*)d_in[2];
    const float* bih_e  = (const float*)d_in[3];
    const float* bhh_e  = (const float*)d_in[4];
    const float* Wih_d  = (const float*)d_in[5];
    const float* Whh_d  = (const float*)d_in[6];
    const float* bih_d  = (const float*)d_in[7];
    const float* bhh_d  = (const float*)d_in[8];
    const float* Wy     = (const float*)d_in[9];
    const float* by     = (const float*)d_in[10];
    float* out = (float*)d_out;

    hipLaunchKernelGGL(prep_kernel, dim3(256), dim3(256), 0, stream,
                       Wih_e, Whh_e, bih_e, bhh_e, Wih_d, Whh_d, bih_d, bhh_d, d_ws);
    hipLaunchKernelGGL(seq2seq_kernel, dim3(NBLOCKS), dim3(NTHREADS), 0, stream,
                       inputs, d_ws, Wy, by, out);
}

// Round 16
// 224.836 us; speedup vs baseline: 1.4125x; 1.0322x over previous
//
#include <hip/hip_runtime.h>

// Seq2seq LSTM, round 16: r15 base (verified PASS, 249us) + double-buffered
// A_frag -> ONE barrier per encoder step (r6 schedule, exonerated by r8's
// bisect: the r6-r8 failures were the gate-split path, not the dbuf schedule).
// Step s reads Abuf[s&1], writes h/x into Abuf[s&1^1] right after trans_cell.
// Decoder: 2 barriers/step (B2 between h-write and y-proj read).
// All else verbatim r15: 256 blocks x 1024 thr x BR=16, full-M MFMA,
// DPP quad-transpose (VALU, no LDS), LDS xstage, pre-scaled weights.
//   i,f,o gates scaled by -log2e -> sigmoid = rcp(1 + exp2(g))
//   g gate scaled by +2*log2e   -> tanh    = 1 - 2*rcp(1 + exp2(g))

#define NTHREADS 1024
#define NBLOCKS  256
#define BR       16

typedef __attribute__((ext_vector_type(8))) short short8;
typedef __attribute__((ext_vector_type(4))) float f32x4;

#define FRAG_ELEMS 51200
#define BIAS_BYTE_OFF 204800
#define L2E 1.4426950408889634f

__device__ __forceinline__ unsigned short f2bf(float f) {
    unsigned int u = __float_as_uint(f);
    return (unsigned short)((u + 0x7fff + ((u >> 16) & 1)) >> 16);   // RNE
}
__device__ __forceinline__ float bf2f(unsigned short s) {
    return __uint_as_float(((unsigned int)s) << 16);
}
__device__ __forceinline__ float ex2(float x) {
    float r; asm("v_exp_f32 %0, %1" : "=v"(r) : "v"(x)); return r;
}
__device__ __forceinline__ float rcpf_(float x) { return __builtin_amdgcn_rcpf(x); }

// quad_perm DPP: lane xor 1 / xor 2 within each quad (full-rate VALU)
__device__ __forceinline__ float dppx1(float x) {
    return __int_as_float(__builtin_amdgcn_mov_dpp(__float_as_int(x), 0xB1, 0xF, 0xF, true));
}
__device__ __forceinline__ float dppx2(float x) {
    return __int_as_float(__builtin_amdgcn_mov_dpp(__float_as_int(x), 0x4E, 0xF, 0xF, true));
}

// r10/r15-verified 4x4 quad transpose + LSTM cell update. Returns h, updates c.
__device__ __forceinline__ float trans_cell(f32x4 v, float& c, int wl) {
    float s0 = dppx1(v[0]), s1 = dppx1(v[1]), s2 = dppx1(v[2]), s3 = dppx1(v[3]);
    const bool o1 = (wl & 1) != 0;
    float a0 = o1 ? s1 : v[0];
    float a1 = o1 ? v[1] : s0;
    float a2 = o1 ? s3 : v[2];
    float a3 = o1 ? v[3] : s2;
    float u0 = dppx2(a0), u1 = dppx2(a1), u2 = dppx2(a2), u3 = dppx2(a3);
    const bool o2 = (wl & 2) != 0;
    float gi = o2 ? u2 : a0;
    float gf = o2 ? u3 : a1;
    float gg = o2 ? a2 : u0;
    float go = o2 ? a3 : u1;
    float si = rcpf_(1.f + ex2(gi));
    float sf = rcpf_(1.f + ex2(gf));
    float tg = fmaf(-2.f, rcpf_(1.f + ex2(gg)), 1.f);
    float so = rcpf_(1.f + ex2(go));
    c = fmaf(sf, c, si * tg);
    float tc = fmaf(-2.f, rcpf_(1.f + ex2(c * (2.f * L2E))), 1.f);
    return so * tc;
}

// frag[((t*4+s)*64 + lane)*8 + e] = scale(gate) * WT'[k][n], bf16
// k = s*32+(lane>>4)*8+e, n = t*16+(lane&15), n = 4*jcol + gate  (r5-identical)
__global__ void prep_kernel(const float* __restrict__ Wih_e, const float* __restrict__ Whh_e,
                            const float* __restrict__ bih_e, const float* __restrict__ bhh_e,
                            const float* __restrict__ Wih_d, const float* __restrict__ Whh_d,
                            const float* __restrict__ bih_d, const float* __restrict__ bhh_d,
                            void* __restrict__ ws)
{
    unsigned short* frag = (unsigned short*)ws;
    float* bias = (float*)((char*)ws + BIAS_BYTE_OFF);
    int gid = blockIdx.x * blockDim.x + threadIdx.x;
    int gsz = gridDim.x * blockDim.x;
    for (int i = gid; i < 2 * FRAG_ELEMS; i += gsz) {
        int which = i / FRAG_ELEMS;
        int e = i - which * FRAG_ELEMS;
        int j8 = e & 7, lane = (e >> 3) & 63, s = (e >> 9) & 3, t = e >> 11;
        int k = s * 32 + (lane >> 4) * 8 + j8;
        int n = t * 16 + (lane & 15);
        int jcol = n >> 2, gate = n & 3, col = gate * 100 + jcol;
        float scale = (gate == 2) ? (2.f * L2E) : -L2E;
        const float* Whh = which ? Whh_d : Whh_e;
        const float* Wih = which ? Wih_d : Wih_e;
        float v = 0.f;
        if (k < 100)      v = Whh[col * 100 + k];
        else if (k < 104) v = Wih[col * 4 + (k - 100)];
        frag[i] = f2bf(v * scale);
    }
    for (int i = gid; i < 800; i += gsz) {
        int which = i / 400, n = i - which * 400;
        int jcol = n >> 2, gate = n & 3, col = gate * 100 + jcol;
        float scale = (gate == 2) ? (2.f * L2E) : -L2E;
        bias[i] = scale * (which ? (bih_d[col] + bhh_d[col]) : (bih_e[col] + bhh_e[col]));
    }
}

__global__ __launch_bounds__(NTHREADS, 4)
void seq2seq_kernel(
    const float* __restrict__ inputs,   // [200][4096][4]
    const void* __restrict__ ws,
    const float* __restrict__ Wy,       // [4][100]
    const float* __restrict__ by_g,     // [4]
    float* __restrict__ out)            // [30][4096][4]
{
    // A (x2 buffers): A[row][k] bf16 at elem ((k>>3)*16+row)*8+(k&7)
    __shared__ unsigned short Abuf[2][2048];     // 8 KB
    __shared__ float Wy_lds[404];
    __shared__ unsigned short xstage[200 * 64];  // 25.6 KB: x[200][16][4] bf16

    const unsigned short* fragE = (const unsigned short*)ws;
    const unsigned short* fragD = fragE + FRAG_ELEMS;
    const float* biasE = (const float*)((const char*)ws + BIAS_BYTE_OFF);
    const float* biasD = biasE + 400;

    const int tid = threadIdx.x;
    const int wid = tid >> 6;          // wave 0..15
    const int wl  = tid & 63;
    const int m   = wl & 15;           // A row / C col
    const int q   = wl >> 4;
    const int blk = blockIdx.x;

    // cell owned after quad transpose (per tile t): row crow, col = 4t+ca
    const int crow = q * 4 + (wl & 3);
    const int ca   = (wl >> 2) & 3;

    for (int i = tid; i < 4096; i += NTHREADS) (&Abuf[0][0])[i] = 0;

    // bulk x staging (vectorized): xstage[s*64 + row*4 + c]
    for (int i = tid; i < 200 * 16; i += NTHREADS) {
        int s = i >> 4, u4 = i & 15;
        float4 v = *(const float4*)&inputs[((size_t)s * 4096 + blk * BR + u4) * 4];
        unsigned int pk01, pk23;
        asm("v_cvt_pk_bf16_f32 %0, %1, %2" : "=v"(pk01) : "v"(v.x), "v"(v.y));
        asm("v_cvt_pk_bf16_f32 %0, %1, %2" : "=v"(pk23) : "v"(v.z), "v"(v.w));
        *(unsigned int*)&xstage[i * 4]     = pk01;
        *(unsigned int*)&xstage[i * 4 + 2] = pk23;
    }

    // x writers: tid 960..1023 -> (row 0..15, comp 0..3)
    const bool isx = (tid >= 960);
    const int xu = tid - 960;
    const int xr = xu >> 2, xc = xu & 3;
    const int xelem = (192 + xr) * 8 + 4 + xc;   // k = 100+xc, row xr

    // weights: up to 2 tiles per wave (t = wid, wid+16; valid t<25)
    short8 bfr[2][4]; float breg[2] = {0.f, 0.f};
    #pragma unroll
    for (int i = 0; i < 2; ++i) {
        int t = wid + 16 * i;
        if (t < 25) {
            #pragma unroll
            for (int s = 0; s < 4; ++s)
                bfr[i][s] = *(const short8*)&fragE[((t * 4 + s) * 64 + wl) * 8];
            breg[i] = biasE[t * 16 + m];
        }
    }
    float cst[2] = {0.f, 0.f};

    __syncthreads();                             // A zeroed + xstage filled
    if (isx) Abuf[0][xelem] = xstage[xu];        // x(0) -> buf 0

    // ---------------- encoder: 200 steps, ONE barrier each ----------------
    for (int step = 0; step < 200; ++step) {
        const int cur = step & 1;
        __syncthreads();                         // buf[cur] complete; buf[cur^1] free
        short8 af[4];
        #pragma unroll
        for (int s = 0; s < 4; ++s)
            af[s] = *(const short8*)&Abuf[cur][(s * 64 + wl) * 8];
        #pragma unroll
        for (int i = 0; i < 2; ++i) {
            int t = wid + 16 * i;
            if (t < 25) {
                f32x4 acc = {breg[i], breg[i], breg[i], breg[i]};
                #pragma unroll
                for (int s = 0; s < 4; ++s)
                    acc = __builtin_amdgcn_mfma_f32_16x16x32_bf16(af[s], bfr[i][s], acc, 0, 0, 0);
                float h = trans_cell(acc, cst[i], wl);
                int col = 4 * t + ca;
                Abuf[cur ^ 1][((col >> 3) * 16 + crow) * 8 + (col & 7)] = f2bf(h);
            }
        }
        if (isx && step < 199)
            Abuf[cur ^ 1][xelem] = xstage[(step + 1) * 64 + xu];   // x(s+1)
    }

    // ---------------- switch to decoder (h_enc is in buf[0]) ----------------
    #pragma unroll
    for (int i = 0; i < 2; ++i) {
        int t = wid + 16 * i;
        if (t < 25) {
            #pragma unroll
            for (int s = 0; s < 4; ++s)
                bfr[i][s] = *(const short8*)&fragD[((t * 4 + s) * 64 + wl) * 8];
            breg[i] = biasD[t * 16 + m];
        }
    }
    cst[0] = cst[1] = 0.f;                       // c resets; h carries over
    if (isx) Abuf[0][xelem] = 0;                 // y_prev = 0 (buf 0, own slot)
    for (int i = tid; i < 404; i += NTHREADS)
        Wy_lds[i] = (i < 400) ? Wy[i] : by_g[i - 400];

    const int yrow = tid >> 5, yln = tid & 31;
    const bool isy = (tid < 512);                // 16 rows x 32 lanes

    // ---------------- decoder: 30 steps, 2 barriers each ----------------
    for (int d = 0; d < 30; ++d) {
        const int cur = d & 1;
        __syncthreads();                         // B1: buf[cur] ready (h, y_prev)
        short8 af[4];
        #pragma unroll
        for (int s = 0; s < 4; ++s)
            af[s] = *(const short8*)&Abuf[cur][(s * 64 + wl) * 8];
        #pragma unroll
        for (int i = 0; i < 2; ++i) {
            int t = wid + 16 * i;
            if (t < 25) {
                f32x4 acc = {breg[i], breg[i], breg[i], breg[i]};
                #pragma unroll
                for (int s = 0; s < 4; ++s)
                    acc = __builtin_amdgcn_mfma_f32_16x16x32_bf16(af[s], bfr[i][s], acc, 0, 0, 0);
                float h = trans_cell(acc, cst[i], wl);
                int col = 4 * t + ca;
                Abuf[cur ^ 1][((col >> 3) * 16 + crow) * 8 + (col & 7)] = f2bf(h);
            }
        }
        __syncthreads();                         // B2: h complete in buf[cur^1]
        if (isy) {
            float p0 = 0.f, p1 = 0.f, p2 = 0.f, p3 = 0.f;
            #pragma unroll
            for (int i = 0; i < 4; ++i) {
                int j = yln + 32 * i;
                if (j < 100) {
                    float hv = bf2f(Abuf[cur ^ 1][((j >> 3) * 16 + yrow) * 8 + (j & 7)]);
                    p0 = fmaf(Wy_lds[0 * 100 + j], hv, p0);
                    p1 = fmaf(Wy_lds[1 * 100 + j], hv, p1);
                    p2 = fmaf(Wy_lds[2 * 100 + j], hv, p2);
                    p3 = fmaf(Wy_lds[3 * 100 + j], hv, p3);
                }
            }
            #pragma unroll
            for (int mm = 16; mm >= 1; mm >>= 1) {
                p0 += __shfl_xor(p0, mm, 32);
                p1 += __shfl_xor(p1, mm, 32);
                p2 += __shfl_xor(p2, mm, 32);
                p3 += __shfl_xor(p3, mm, 32);
            }
            if (yln == 0) {
                float y0 = p0 + Wy_lds[400], y1 = p1 + Wy_lds[401];
                float y2 = p2 + Wy_lds[402], y3 = p3 + Wy_lds[403];
                float4 yv = make_float4(y0, y1, y2, y3);
                *(float4*)&out[((size_t)d * 4096 + blk * BR + yrow) * 4] = yv;
                unsigned int pk01, pk23;
                asm("v_cvt_pk_bf16_f32 %0, %1, %2" : "=v"(pk01) : "v"(y0), "v"(y1));
                asm("v_cvt_pk_bf16_f32 %0, %1, %2" : "=v"(pk23) : "v"(y2), "v"(y3));
                *(unsigned int*)&Abuf[cur ^ 1][(192 + yrow) * 8 + 4] = pk01;  // y feedback
                *(unsigned int*)&Abuf[cur ^ 1][(192 + yrow) * 8 + 6] = pk23;
            }
        }
    }
}

extern "C" void kernel_launch(void* const* d_in, const int* in_sizes, int n_in,
                              void* d_out, int out_size, void* d_ws, size_t ws_size,
                              hipStream_t stream)
{
    (void)in_sizes; (void)n_in; (void)out_size; (void)ws_size;
    const float* inputs = (const float*)d_in[0];
    const float* Wih_e  = (const float*)d_in[1];
    const float* Whh_e  = (const float*)d_in[2];
    const float* bih_e  = (const float*)d_in[3];
    const float* bhh_e  = (const float*)d_in[4];
    const float* Wih_d  = (const float*)d_in[5];
    const float* Whh_d  = (const float*)d_in[6];
    const float* bih_d  = (const float*)d_in[7];
    const float* bhh_d  = (const float*)d_in[8];
    const float* Wy     = (const float*)d_in[9];
    const float* by     = (const float*)d_in[10];
    float* out = (float*)d_out;

    hipLaunchKernelGGL(prep_kernel, dim3(256), dim3(256), 0, stream,
                       Wih_e, Whh_e, bih_e, bhh_e, Wih_d, Whh_d, bih_d, bhh_d, d_ws);
    hipLaunchKernelGGL(seq2seq_kernel, dim3(NBLOCKS), dim3(NTHREADS), 0, stream,
                       inputs, d_ws, Wy, by, out);
}

// Round 17
// 211.608 us; speedup vs baseline: 1.5007x; 1.0625x over previous
//
#include <hip/hip_runtime.h>

// Seq2seq LSTM, round 17: r16 (verified PASS, 243us) + VALU shaving.
// (1) h-store: manual-RNE f2bf (5 ops) -> v_cvt_pk_bf16_f32 (1 op, HW RNE).
// (2) encoder/decoder unrolled x2 with static double-buffer pointers (no
//     per-step cur-select address chains).
// Everything else byte-identical to r16: 256 blocks x 1024 thr x BR=16,
// full-M MFMA, DPP quad-transpose, 1 barrier/enc step, LDS xstage.
//   i,f,o gates scaled by -log2e -> sigmoid = rcp(1 + exp2(g))
//   g gate scaled by +2*log2e   -> tanh    = 1 - 2*rcp(1 + exp2(g))

#define NTHREADS 1024
#define NBLOCKS  256
#define BR       16

typedef __attribute__((ext_vector_type(8))) short short8;
typedef __attribute__((ext_vector_type(4))) float f32x4;

#define FRAG_ELEMS 51200
#define BIAS_BYTE_OFF 204800
#define L2E 1.4426950408889634f

__device__ __forceinline__ unsigned short f2bf(float f) {
    unsigned int u = __float_as_uint(f);
    return (unsigned short)((u + 0x7fff + ((u >> 16) & 1)) >> 16);   // RNE
}
__device__ __forceinline__ float bf2f(unsigned short s) {
    return __uint_as_float(((unsigned int)s) << 16);
}
__device__ __forceinline__ unsigned short cvt1bf(float f) {     // 1-op HW RNE
    unsigned int pk;
    asm("v_cvt_pk_bf16_f32 %0, %1, %2" : "=v"(pk) : "v"(f), "v"(f));
    return (unsigned short)pk;
}
__device__ __forceinline__ float ex2(float x) {
    float r; asm("v_exp_f32 %0, %1" : "=v"(r) : "v"(x)); return r;
}
__device__ __forceinline__ float rcpf_(float x) { return __builtin_amdgcn_rcpf(x); }

__device__ __forceinline__ float dppx1(float x) {
    return __int_as_float(__builtin_amdgcn_mov_dpp(__float_as_int(x), 0xB1, 0xF, 0xF, true));
}
__device__ __forceinline__ float dppx2(float x) {
    return __int_as_float(__builtin_amdgcn_mov_dpp(__float_as_int(x), 0x4E, 0xF, 0xF, true));
}

// r10/r15-verified 4x4 quad transpose + LSTM cell update. Returns h, updates c.
__device__ __forceinline__ float trans_cell(f32x4 v, float& c, int wl) {
    float s0 = dppx1(v[0]), s1 = dppx1(v[1]), s2 = dppx1(v[2]), s3 = dppx1(v[3]);
    const bool o1 = (wl & 1) != 0;
    float a0 = o1 ? s1 : v[0];
    float a1 = o1 ? v[1] : s0;
    float a2 = o1 ? s3 : v[2];
    float a3 = o1 ? v[3] : s2;
    float u0 = dppx2(a0), u1 = dppx2(a1), u2 = dppx2(a2), u3 = dppx2(a3);
    const bool o2 = (wl & 2) != 0;
    float gi = o2 ? u2 : a0;
    float gf = o2 ? u3 : a1;
    float gg = o2 ? a2 : u0;
    float go = o2 ? a3 : u1;
    float si = rcpf_(1.f + ex2(gi));
    float sf = rcpf_(1.f + ex2(gf));
    float tg = fmaf(-2.f, rcpf_(1.f + ex2(gg)), 1.f);
    float so = rcpf_(1.f + ex2(go));
    c = fmaf(sf, c, si * tg);
    float tc = fmaf(-2.f, rcpf_(1.f + ex2(c * (2.f * L2E))), 1.f);
    return so * tc;
}

// frag[((t*4+s)*64 + lane)*8 + e] = scale(gate) * WT'[k][n], bf16  (r5-identical)
__global__ void prep_kernel(const float* __restrict__ Wih_e, const float* __restrict__ Whh_e,
                            const float* __restrict__ bih_e, const float* __restrict__ bhh_e,
                            const float* __restrict__ Wih_d, const float* __restrict__ Whh_d,
                            const float* __restrict__ bih_d, const float* __restrict__ bhh_d,
                            void* __restrict__ ws)
{
    unsigned short* frag = (unsigned short*)ws;
    float* bias = (float*)((char*)ws + BIAS_BYTE_OFF);
    int gid = blockIdx.x * blockDim.x + threadIdx.x;
    int gsz = gridDim.x * blockDim.x;
    for (int i = gid; i < 2 * FRAG_ELEMS; i += gsz) {
        int which = i / FRAG_ELEMS;
        int e = i - which * FRAG_ELEMS;
        int j8 = e & 7, lane = (e >> 3) & 63, s = (e >> 9) & 3, t = e >> 11;
        int k = s * 32 + (lane >> 4) * 8 + j8;
        int n = t * 16 + (lane & 15);
        int jcol = n >> 2, gate = n & 3, col = gate * 100 + jcol;
        float scale = (gate == 2) ? (2.f * L2E) : -L2E;
        const float* Whh = which ? Whh_d : Whh_e;
        const float* Wih = which ? Wih_d : Wih_e;
        float v = 0.f;
        if (k < 100)      v = Whh[col * 100 + k];
        else if (k < 104) v = Wih[col * 4 + (k - 100)];
        frag[i] = f2bf(v * scale);
    }
    for (int i = gid; i < 800; i += gsz) {
        int which = i / 400, n = i - which * 400;
        int jcol = n >> 2, gate = n & 3, col = gate * 100 + jcol;
        float scale = (gate == 2) ? (2.f * L2E) : -L2E;
        bias[i] = scale * (which ? (bih_d[col] + bhh_d[col]) : (bih_e[col] + bhh_e[col]));
    }
}

__global__ __launch_bounds__(NTHREADS, 4)
void seq2seq_kernel(
    const float* __restrict__ inputs,   // [200][4096][4]
    const void* __restrict__ ws,
    const float* __restrict__ Wy,       // [4][100]
    const float* __restrict__ by_g,     // [4]
    float* __restrict__ out)            // [30][4096][4]
{
    __shared__ unsigned short Abuf[2][2048];     // 8 KB
    __shared__ float Wy_lds[404];
    __shared__ unsigned short xstage[200 * 64];  // 25.6 KB

    const unsigned short* fragE = (const unsigned short*)ws;
    const unsigned short* fragD = fragE + FRAG_ELEMS;
    const float* biasE = (const float*)((const char*)ws + BIAS_BYTE_OFF);
    const float* biasD = biasE + 400;

    const int tid = threadIdx.x;
    const int wid = tid >> 6;          // wave 0..15
    const int wl  = tid & 63;
    const int m   = wl & 15;
    const int q   = wl >> 4;
    const int blk = blockIdx.x;

    const int crow = q * 4 + (wl & 3);
    const int ca   = (wl >> 2) & 3;

    for (int i = tid; i < 4096; i += NTHREADS) (&Abuf[0][0])[i] = 0;

    for (int i = tid; i < 200 * 16; i += NTHREADS) {
        int s = i >> 4, u4 = i & 15;
        float4 v = *(const float4*)&inputs[((size_t)s * 4096 + blk * BR + u4) * 4];
        unsigned int pk01, pk23;
        asm("v_cvt_pk_bf16_f32 %0, %1, %2" : "=v"(pk01) : "v"(v.x), "v"(v.y));
        asm("v_cvt_pk_bf16_f32 %0, %1, %2" : "=v"(pk23) : "v"(v.z), "v"(v.w));
        *(unsigned int*)&xstage[i * 4]     = pk01;
        *(unsigned int*)&xstage[i * 4 + 2] = pk23;
    }

    const bool isx = (tid >= 960);
    const int xu = tid - 960;
    const int xr = xu >> 2, xc = xu & 3;
    const int xelem = (192 + xr) * 8 + 4 + xc;

    short8 bfr[2][4]; float breg[2] = {0.f, 0.f};
    #pragma unroll
    for (int i = 0; i < 2; ++i) {
        int t = wid + 16 * i;
        if (t < 25) {
            #pragma unroll
            for (int s = 0; s < 4; ++s)
                bfr[i][s] = *(const short8*)&fragE[((t * 4 + s) * 64 + wl) * 8];
            breg[i] = biasE[t * 16 + m];
        }
    }
    float cst[2] = {0.f, 0.f};

    // one encoder step: read Ar, write h into Aw, stage x(step+1) into Aw
    auto enc_body = [&](const unsigned short* Ar, unsigned short* Aw, int step) {
        __syncthreads();                         // Ar complete; Aw free
        short8 af[4];
        #pragma unroll
        for (int s = 0; s < 4; ++s)
            af[s] = *(const short8*)&Ar[(s * 64 + wl) * 8];
        #pragma unroll
        for (int i = 0; i < 2; ++i) {
            int t = wid + 16 * i;
            if (t < 25) {
                f32x4 acc = {breg[i], breg[i], breg[i], breg[i]};
                #pragma unroll
                for (int s = 0; s < 4; ++s)
                    acc = __builtin_amdgcn_mfma_f32_16x16x32_bf16(af[s], bfr[i][s], acc, 0, 0, 0);
                float h = trans_cell(acc, cst[i], wl);
                int col = 4 * t + ca;
                Aw[((col >> 3) * 16 + crow) * 8 + (col & 7)] = cvt1bf(h);
            }
        }
        if (isx && step < 199)
            Aw[xelem] = xstage[(step + 1) * 64 + xu];
    };

    __syncthreads();                             // A zeroed + xstage filled
    if (isx) Abuf[0][xelem] = xstage[xu];        // x(0) -> buf 0

    // ---------------- encoder: 200 steps, unrolled x2 ----------------
    for (int step = 0; step < 200; step += 2) {
        enc_body(Abuf[0], Abuf[1], step);
        enc_body(Abuf[1], Abuf[0], step + 1);
    }

    // ---------------- switch to decoder (h_enc in buf[0]) ----------------
    #pragma unroll
    for (int i = 0; i < 2; ++i) {
        int t = wid + 16 * i;
        if (t < 25) {
            #pragma unroll
            for (int s = 0; s < 4; ++s)
                bfr[i][s] = *(const short8*)&fragD[((t * 4 + s) * 64 + wl) * 8];
            breg[i] = biasD[t * 16 + m];
        }
    }
    cst[0] = cst[1] = 0.f;
    if (isx) Abuf[0][xelem] = 0;                 // y_prev = 0
    for (int i = tid; i < 404; i += NTHREADS)
        Wy_lds[i] = (i < 400) ? Wy[i] : by_g[i - 400];

    const int yrow = tid >> 5, yln = tid & 31;
    const bool isy = (tid < 512);

    auto dec_body = [&](const unsigned short* Ar, unsigned short* Aw, int d) {
        __syncthreads();                         // B1: Ar ready (h, y_prev)
        short8 af[4];
        #pragma unroll
        for (int s = 0; s < 4; ++s)
            af[s] = *(const short8*)&Ar[(s * 64 + wl) * 8];
        #pragma unroll
        for (int i = 0; i < 2; ++i) {
            int t = wid + 16 * i;
            if (t < 25) {
                f32x4 acc = {breg[i], breg[i], breg[i], breg[i]};
                #pragma unroll
                for (int s = 0; s < 4; ++s)
                    acc = __builtin_amdgcn_mfma_f32_16x16x32_bf16(af[s], bfr[i][s], acc, 0, 0, 0);
                float h = trans_cell(acc, cst[i], wl);
                int col = 4 * t + ca;
                Aw[((col >> 3) * 16 + crow) * 8 + (col & 7)] = cvt1bf(h);
            }
        }
        __syncthreads();                         // B2: h complete in Aw
        if (isy) {
            float p0 = 0.f, p1 = 0.f, p2 = 0.f, p3 = 0.f;
            #pragma unroll
            for (int i = 0; i < 4; ++i) {
                int j = yln + 32 * i;
                if (j < 100) {
                    float hv = bf2f(Aw[((j >> 3) * 16 + yrow) * 8 + (j & 7)]);
                    p0 = fmaf(Wy_lds[0 * 100 + j], hv, p0);
                    p1 = fmaf(Wy_lds[1 * 100 + j], hv, p1);
                    p2 = fmaf(Wy_lds[2 * 100 + j], hv, p2);
                    p3 = fmaf(Wy_lds[3 * 100 + j], hv, p3);
                }
            }
            #pragma unroll
            for (int mm = 16; mm >= 1; mm >>= 1) {
                p0 += __shfl_xor(p0, mm, 32);
                p1 += __shfl_xor(p1, mm, 32);
                p2 += __shfl_xor(p2, mm, 32);
                p3 += __shfl_xor(p3, mm, 32);
            }
            if (yln == 0) {
                float y0 = p0 + Wy_lds[400], y1 = p1 + Wy_lds[401];
                float y2 = p2 + Wy_lds[402], y3 = p3 + Wy_lds[403];
                *(float4*)&out[((size_t)d * 4096 + blk * BR + yrow) * 4] =
                    make_float4(y0, y1, y2, y3);
                unsigned int pk01, pk23;
                asm("v_cvt_pk_bf16_f32 %0, %1, %2" : "=v"(pk01) : "v"(y0), "v"(y1));
                asm("v_cvt_pk_bf16_f32 %0, %1, %2" : "=v"(pk23) : "v"(y2), "v"(y3));
                *(unsigned int*)&Aw[(192 + yrow) * 8 + 4] = pk01;   // y feedback
                *(unsigned int*)&Aw[(192 + yrow) * 8 + 6] = pk23;
            }
        }
    };

    // ---------------- decoder: 30 steps, unrolled x2 ----------------
    for (int d = 0; d < 30; d += 2) {
        dec_body(Abuf[0], Abuf[1], d);
        dec_body(Abuf[1], Abuf[0], d + 1);
    }
}

extern "C" void kernel_launch(void* const* d_in, const int* in_sizes, int n_in,
                              void* d_out, int out_size, void* d_ws, size_t ws_size,
                              hipStream_t stream)
{
    (void)in_sizes; (void)n_in; (void)out_size; (void)ws_size;
    const float* inputs = (const float*)d_in[0];
    const float* Wih_e  = (const float*)d_in[1];
    const float* Whh_e  = (const float*)d_in[2];
    const float* bih_e  = (const float*)d_in[3];
    const float* bhh_e  = (const float*)d_in[4];
    const float* Wih_d  = (const float*)d_in[5];
    const float* Whh_d  = (const float*)d_in[6];
    const float* bih_d  = (const float*)d_in[7];
    const float* bhh_d  = (const float*)d_in[8];
    const float* Wy     = (const float*)d_in[9];
    const float* by     = (const float*)d_in[10];
    float* out = (float*)d_out;

    hipLaunchKernelGGL(prep_kernel, dim3(256), dim3(256), 0, stream,
                       Wih_e, Whh_e, bih_e, bhh_e, Wih_d, Whh_d, bih_d, bhh_d, d_ws);
    hipLaunchKernelGGL(seq2seq_kernel, dim3(NBLOCKS), dim3(NTHREADS), 0, stream,
                       inputs, d_ws, Wy, by, out);
}